// Round 1
// baseline (797.805 us; speedup 1.0000x reference)
//
#include <hip/hip_runtime.h>
#include <hip/hip_cooperative_groups.h>
#include <math.h>

namespace cg = cooperative_groups;

#define NN 2048
#define MAX_ITER 1000
#define TOLF 1e-6f
#define TPB 512
#define NBLK 256
#define WPB 8   // waves per block; NBLK*WPB == NN (one wave per row)

__global__ __launch_bounds__(TPB, 1)
void xgr_sinkhorn(const float* __restrict__ Mm,
                  const float* __restrict__ Gg,
                  const int* __restrict__ eps_p,
                  float* __restrict__ out,
                  float* __restrict__ ws)
{
    cg::grid_group grid = cg::this_grid();

    // workspace layout (ws is 8-byte aligned from hipMalloc):
    // [0,NN)        f buffer 0
    // [NN,2NN)      f buffer 1
    // [2NN,2NN+128) int flags (one per convergence check)
    // then          double accumulator
    float*  f0    = ws;
    float*  f1    = ws + NN;
    int*    flags = (int*)(ws + 2 * NN);
    double* acc   = (double*)(ws + 2 * NN + 128);

    const int tid  = threadIdx.x;
    const int lane = tid & 63;
    const int wave = tid >> 6;
    const int row  = blockIdx.x * WPB + wave;   // 0..2047, one wave owns one row
    const int gtid = blockIdx.x * TPB + tid;

    // init (ws is poisoned 0xAA before every call)
    if (gtid < NN)  f0[gtid] = 0.0f;
    if (gtid < 128) flags[gtid] = 0;
    if (gtid == 0)  *acc = 0.0;

    // eps decode: python scalar 1 arrives as an integer array; tolerate f32 too.
    const int ebits = *eps_p;
    const float eps = (ebits >= 1 && ebits <= (1 << 20)) ? (float)ebits
                                                         : __int_as_float(ebits);
    const float inv_eps = 1.0f / eps;

    grid.sync();

    const float4* Mrow = (const float4*)(Mm + (size_t)row * NN);

    float* fcur = f0;   // f_t
    float* fnxt = f1;   // f_{t+1}

    __shared__ int s_flag;

    // Pass t computes L_i = LSE_j((f_t[j] - M_ij)/eps); gives both the update
    // f_{t+1} = 0.5*(f_t - eps*L) and (fused, free) the reference's convergence
    // check for body iteration k = t-1: row_sum_i = exp(f_t[i]/eps + L_i).
    for (int t = 0; t < MAX_ITER; ++t) {
        const float4* fv = (const float4*)fcur;
        float x[32];                 // statically indexed -> stays in VGPRs
        float mloc = -INFINITY;
        #pragma unroll
        for (int k = 0; k < 8; ++k) {
            const int idx = (k << 6) + lane;        // coalesced 1KB/wave/instr
            const float4 mv = Mrow[idx];
            const float4 f4 = fv[idx];
            const float x0 = (f4.x - mv.x) * inv_eps;
            const float x1 = (f4.y - mv.y) * inv_eps;
            const float x2 = (f4.z - mv.z) * inv_eps;
            const float x3 = (f4.w - mv.w) * inv_eps;
            x[4*k+0] = x0; x[4*k+1] = x1; x[4*k+2] = x2; x[4*k+3] = x3;
            mloc = fmaxf(mloc, fmaxf(fmaxf(x0, x1), fmaxf(x2, x3)));
        }
        // wave max
        float mw = mloc;
        #pragma unroll
        for (int off = 32; off; off >>= 1)
            mw = fmaxf(mw, __shfl_down(mw, off));
        mw = __shfl(mw, 0);
        // sum of exp(x - max)
        float s = 0.0f;
        #pragma unroll
        for (int k = 0; k < 32; ++k) s += expf(x[k] - mw);
        #pragma unroll
        for (int off = 32; off; off >>= 1)
            s += __shfl_down(s, off);

        if (lane == 0) {
            const float L  = mw + logf(s);
            const float fi = fcur[row];
            fnxt[row] = 0.5f * (fi - eps * L);
            if ((t % 10) == 1) {   // reference check at k=t-1 (k%10==0)
                const float rs = expf(fi * inv_eps + L);
                if (!(fabsf(rs - 1.0f) < TOLF))
                    atomicOr(&flags[(t - 1) / 10], 1);
            }
        }
        grid.sync();
        if ((t % 10) == 1) {
            if (tid == 0)
                s_flag = __hip_atomic_load(&flags[(t - 1) / 10],
                                           __ATOMIC_RELAXED,
                                           __HIP_MEMORY_SCOPE_AGENT);
            __syncthreads();
            if (s_flag == 0) break;  // converged: final f is fcur (= f_t)
        }
        float* tmp = fcur; fcur = fnxt; fnxt = tmp;
    }
    // If loop ran all MAX_ITER passes: 1000 swaps -> fcur = f_1000. Correct.

    // ---- loss epilogue: sum_ij g*(log g - logQ - 1) + exp(logQ), logQ=(f_i+f_j-M)/eps
    const float4* Grow = (const float4*)(Gg + (size_t)row * NN);
    const float4* fvf  = (const float4*)fcur;
    const float   fi   = fcur[row];
    double lsum = 0.0;
    #pragma unroll
    for (int k = 0; k < 8; ++k) {
        const int idx = (k << 6) + lane;
        const float4 mv = Mrow[idx];
        const float4 gv = Grow[idx];
        const float4 f4 = fvf[idx];
        {
            const float lq = (fi + f4.x - mv.x) * inv_eps;
            lsum += (double)(gv.x * (logf(gv.x) - lq - 1.0f) + expf(lq));
        }
        {
            const float lq = (fi + f4.y - mv.y) * inv_eps;
            lsum += (double)(gv.y * (logf(gv.y) - lq - 1.0f) + expf(lq));
        }
        {
            const float lq = (fi + f4.z - mv.z) * inv_eps;
            lsum += (double)(gv.z * (logf(gv.z) - lq - 1.0f) + expf(lq));
        }
        {
            const float lq = (fi + f4.w - mv.w) * inv_eps;
            lsum += (double)(gv.w * (logf(gv.w) - lq - 1.0f) + expf(lq));
        }
    }
    #pragma unroll
    for (int off = 32; off; off >>= 1)
        lsum += __shfl_down(lsum, off);

    __shared__ double s_part[WPB];
    if (lane == 0) s_part[wave] = lsum;
    __syncthreads();
    if (tid == 0) {
        double b = 0.0;
        #pragma unroll
        for (int w = 0; w < WPB; ++w) b += s_part[w];
        atomicAdd(acc, b);
    }
    grid.sync();
    if (gtid == 0) {
        const double total = __hip_atomic_load(acc, __ATOMIC_RELAXED,
                                               __HIP_MEMORY_SCOPE_AGENT);
        out[0] = (float)(250.0 * total);
    }
}

extern "C" void kernel_launch(void* const* d_in, const int* in_sizes, int n_in,
                              void* d_out, int out_size, void* d_ws, size_t ws_size,
                              hipStream_t stream)
{
    const float* Mm    = (const float*)d_in[0];
    const float* Gg    = (const float*)d_in[1];
    const int*   eps_p = (const int*)d_in[2];
    float* out = (float*)d_out;
    float* ws  = (float*)d_ws;

    void* args[] = { (void*)&Mm, (void*)&Gg, (void*)&eps_p, (void*)&out, (void*)&ws };
    hipLaunchCooperativeKernel((void*)xgr_sinkhorn, dim3(NBLK), dim3(TPB),
                               args, 0, stream);
}

// Round 2
// 403.183 us; speedup vs baseline: 1.9788x; 1.9788x over previous
//
#include <hip/hip_runtime.h>
#include <hip/hip_cooperative_groups.h>
#include <math.h>

namespace cg = cooperative_groups;

#define NN 2048
#define MAX_ITER 1000
#define TOLF 1e-6f
#define TPB 512
#define NBLK 256
#define WPB 8            // waves per block; NBLK*WPB == NN (one wave per row)
#define NSHARD 8         // barrier shards (≈ per-XCD)
#define BPS (NBLK / NSHARD)

__global__ __launch_bounds__(TPB, 1)
void xgr_sinkhorn(const float* __restrict__ Mm,
                  const float* __restrict__ Gg,
                  const int* __restrict__ eps_p,
                  float* __restrict__ out,
                  float* __restrict__ ws)
{
    // ---- LDS: M rows staged once (survive L2 invalidations), f staged per pass
    __shared__ float  m_lds[WPB][NN];   // 64 KB
    __shared__ float  f_lds[NN];        // 8 KB
    __shared__ int    s_flag;
    __shared__ double s_part[WPB];

    // ---- workspace layout (poisoned 0xAA before every call; init below)
    float* f0        = ws;
    float* f1        = ws + NN;
    int*   flags     = (int*)(ws + 2 * NN);     // [0,128): one per convergence check
    int*   shard_cnt = flags + 128;             // 8 shards, stride 32 ints (128 B)
    int*   top_cnt   = shard_cnt + NSHARD * 32; // single int (padded)
    int*   genp      = top_cnt + 32;            // barrier generation (padded)
    double* acc      = (double*)(genp + 32);    // byte offset (4096+448)*4, 8B-aligned

    const int tid  = threadIdx.x;
    const int lane = tid & 63;
    const int wave = tid >> 6;
    const int row  = blockIdx.x * WPB + wave;
    const int gtid = blockIdx.x * TPB + tid;

    // init shared state
    if (gtid < NN)  f0[gtid] = 0.0f;
    if (gtid < 448) flags[gtid] = 0;            // flags + all barrier counters (contiguous ints)
    if (gtid == 0)  *acc = 0.0;

    const int ebits = *eps_p;
    const float eps = (ebits >= 1 && ebits <= (1 << 20)) ? (float)ebits
                                                         : __int_as_float(ebits);
    const float inv_eps = 1.0f / eps;

    // stage this block's 8 M rows into LDS (once)
    {
        const float4* Mrow = (const float4*)(Mm + (size_t)row * NN);
        float4* ml4 = (float4*)m_lds[wave];
        #pragma unroll
        for (int k = 0; k < 8; ++k) {
            const int idx = (k << 6) + lane;
            ml4[idx] = Mrow[idx];
        }
    }

    cg::this_grid().sync();   // init + staging visible grid-wide; custom barrier takes over

    // ---- lightweight hierarchical grid barrier (monotone counters, no resets)
    int bar = 0;
    auto grid_barrier = [&](int target) {
        __syncthreads();                       // block stores drained (vmcnt 0)
        if (threadIdx.x == 0) {
            __threadfence();                   // release: flush our XCD L2 to IF
            const int sh = (int)blockIdx.x & (NSHARD - 1);
            int prev = __hip_atomic_fetch_add(&shard_cnt[sh * 32], 1,
                                              __ATOMIC_RELAXED, __HIP_MEMORY_SCOPE_AGENT);
            if (prev == target * BPS - 1) {    // last in shard this round
                __threadfence();
                int p2 = __hip_atomic_fetch_add(top_cnt, 1,
                                                __ATOMIC_RELAXED, __HIP_MEMORY_SCOPE_AGENT);
                if (p2 == target * NSHARD - 1) {   // last shard: release everyone
                    __threadfence();
                    __hip_atomic_store(genp, target,
                                       __ATOMIC_RELAXED, __HIP_MEMORY_SCOPE_AGENT);
                }
            }
            int guard = 0;
            while (__hip_atomic_load(genp, __ATOMIC_RELAXED,
                                     __HIP_MEMORY_SCOPE_AGENT) < target) {
                __builtin_amdgcn_s_sleep(1);
                if (++guard > (1 << 23)) break;   // safety net: fail loud, don't hang
            }
            __threadfence();                   // acquire: invalidate L1/L2, see fresh f
        }
        __syncthreads();
    };

    float* fcur = f0;   // f_t
    float* fnxt = f1;   // f_{t+1}

    // Pass t: L_i = LSE_j((f_t[j] - M_ij)/eps) -> update f_{t+1} = 0.5*(f_t - eps*L)
    // and (fused, free) the reference's convergence check for body iter k = t-1:
    // row_sum_i = exp(f_t[i]/eps + L_i).
    for (int t = 0; t < MAX_ITER; ++t) {
        // stage f_t into LDS: one coalesced float4 per thread (8 KB/block from IF)
        ((float4*)f_lds)[tid] = ((const float4*)fcur)[tid];
        __syncthreads();

        const float4* ml4 = (const float4*)m_lds[wave];
        const float4* fl4 = (const float4*)f_lds;
        float x[32];
        float mloc = -INFINITY;
        #pragma unroll
        for (int k = 0; k < 8; ++k) {
            const int idx = (k << 6) + lane;
            const float4 mv = ml4[idx];
            const float4 f4 = fl4[idx];
            const float x0 = (f4.x - mv.x) * inv_eps;
            const float x1 = (f4.y - mv.y) * inv_eps;
            const float x2 = (f4.z - mv.z) * inv_eps;
            const float x3 = (f4.w - mv.w) * inv_eps;
            x[4*k+0] = x0; x[4*k+1] = x1; x[4*k+2] = x2; x[4*k+3] = x3;
            mloc = fmaxf(mloc, fmaxf(fmaxf(x0, x1), fmaxf(x2, x3)));
        }
        float mw = mloc;
        #pragma unroll
        for (int off = 32; off; off >>= 1)
            mw = fmaxf(mw, __shfl_down(mw, off));
        mw = __shfl(mw, 0);
        float s = 0.0f;
        #pragma unroll
        for (int k = 0; k < 32; ++k) s += expf(x[k] - mw);
        #pragma unroll
        for (int off = 32; off; off >>= 1)
            s += __shfl_down(s, off);

        if (lane == 0) {
            const float L  = mw + logf(s);
            const float fi = f_lds[row];
            fnxt[row] = 0.5f * (fi - eps * L);
            if ((t % 10) == 1) {   // reference check at k = t-1 (k%10==0)
                const float rs = expf(fi * inv_eps + L);
                if (!(fabsf(rs - 1.0f) < TOLF))
                    atomicOr(&flags[(t - 1) / 10], 1);
            }
        }

        grid_barrier(++bar);

        if ((t % 10) == 1) {
            if (tid == 0)
                s_flag = __hip_atomic_load(&flags[(t - 1) / 10],
                                           __ATOMIC_RELAXED, __HIP_MEMORY_SCOPE_AGENT);
            __syncthreads();
            if (s_flag == 0) break;   // converged: final f is fcur (= f_t)
        }
        float* tmp = fcur; fcur = fnxt; fnxt = tmp;
    }
    // MAX_ITER exhaustion: 1000 swaps -> fcur = f_1000. Correct.

    // ---- loss epilogue: sum_ij g*(log g - logQ - 1) + exp(logQ); logQ=(f_i+f_j-M)/eps
    __syncthreads();                           // everyone out of the loop
    ((float4*)f_lds)[tid] = ((const float4*)fcur)[tid];   // final f into LDS
    __syncthreads();

    const float4* Grow = (const float4*)(Gg + (size_t)row * NN);
    const float4* ml4  = (const float4*)m_lds[wave];
    const float4* fl4  = (const float4*)f_lds;
    const float   fi   = f_lds[row];
    double lsum = 0.0;
    #pragma unroll
    for (int k = 0; k < 8; ++k) {
        const int idx = (k << 6) + lane;
        const float4 mv = ml4[idx];
        const float4 gv = Grow[idx];
        const float4 f4 = fl4[idx];
        {
            const float lq = (fi + f4.x - mv.x) * inv_eps;
            lsum += (double)(gv.x * (logf(gv.x) - lq - 1.0f) + expf(lq));
        }
        {
            const float lq = (fi + f4.y - mv.y) * inv_eps;
            lsum += (double)(gv.y * (logf(gv.y) - lq - 1.0f) + expf(lq));
        }
        {
            const float lq = (fi + f4.z - mv.z) * inv_eps;
            lsum += (double)(gv.z * (logf(gv.z) - lq - 1.0f) + expf(lq));
        }
        {
            const float lq = (fi + f4.w - mv.w) * inv_eps;
            lsum += (double)(gv.w * (logf(gv.w) - lq - 1.0f) + expf(lq));
        }
    }
    #pragma unroll
    for (int off = 32; off; off >>= 1)
        lsum += __shfl_down(lsum, off);

    if (lane == 0) s_part[wave] = lsum;
    __syncthreads();
    if (tid == 0) {
        double b = 0.0;
        #pragma unroll
        for (int w = 0; w < WPB; ++w) b += s_part[w];
        atomicAdd(acc, b);
    }

    grid_barrier(++bar);

    if (gtid == 0) {
        const double total = __hip_atomic_load(acc, __ATOMIC_RELAXED,
                                               __HIP_MEMORY_SCOPE_AGENT);
        out[0] = (float)(250.0 * total);
    }
}

extern "C" void kernel_launch(void* const* d_in, const int* in_sizes, int n_in,
                              void* d_out, int out_size, void* d_ws, size_t ws_size,
                              hipStream_t stream)
{
    const float* Mm    = (const float*)d_in[0];
    const float* Gg    = (const float*)d_in[1];
    const int*   eps_p = (const int*)d_in[2];
    float* out = (float*)d_out;
    float* ws  = (float*)d_ws;

    void* args[] = { (void*)&Mm, (void*)&Gg, (void*)&eps_p, (void*)&out, (void*)&ws };
    hipLaunchCooperativeKernel((void*)xgr_sinkhorn, dim3(NBLK), dim3(TPB),
                               args, 0, stream);
}

// Round 4
// 240.222 us; speedup vs baseline: 3.3211x; 1.6784x over previous
//
#include <hip/hip_runtime.h>
#include <hip/hip_cooperative_groups.h>
#include <math.h>

namespace cg = cooperative_groups;

#define NN 2048
#define MAX_ITER 1000
#define TOLF 1e-6f
#define TPB 512
#define NBLK 256
#define WPB 8              // waves per block; NBLK*WPB == NN (one wave per row)
#define SPIN_LIMIT (1 << 14)

// pair word: [63:33]=tag (pass number), [32]=viol bit, [31:0]=f32 bits
__device__ __forceinline__ unsigned long long pack_pair(unsigned int tag,
                                                        unsigned int viol,
                                                        float v) {
    return ((unsigned long long)((tag << 1) | viol) << 32) | (unsigned long long)__float_as_uint(v);
}

__global__ __launch_bounds__(TPB, 1)
void xgr_sinkhorn(const float* __restrict__ Mm,
                  const float* __restrict__ Gg,
                  const int* __restrict__ eps_p,
                  float* __restrict__ out,
                  unsigned long long* __restrict__ ws64)
{
    __shared__ float  m_lds[WPB][NN];   // 64 KB: this block's 8 M rows
    __shared__ float  fA[NN], fB[NN];   // 8 KB each: f_t staging, double-buffered
    __shared__ int    s_stale[WPB];
    __shared__ int    s_viol[WPB];
    __shared__ int    s_abort;
    __shared__ double s_part[WPB];

    // workspace: two tagged f buffers (by pass parity), then accumulator/counters
    unsigned long long* gb0 = ws64;         // holds f_t for even t
    unsigned long long* gb1 = ws64 + NN;    // odd t
    double* acc      = (double*)(ws64 + 2 * NN);
    int*    done_cnt = (int*)(ws64 + 2 * NN + 1);
    int*    abortp   = (int*)(ws64 + 2 * NN + 2);

    const int tid  = threadIdx.x;
    const int lane = tid & 63;
    const int wave = tid >> 6;
    const int row  = blockIdx.x * WPB + wave;
    const int gtid = blockIdx.x * TPB + tid;

    // init: each block owns its 8 rows' slots in both buffers
    if (tid < WPB) {
        const int r = blockIdx.x * WPB + tid;
        gb0[r] = 0ULL;                        // f_0 = 0.0f, tag 0, viol 0
        gb1[r] = 0xFFFFFFFF00000000ULL;       // invalid tag
    }
    if (gtid == 0) { *acc = 0.0; *done_cnt = 0; *abortp = 0; }
    if (tid == 0)  s_abort = 0;

    const int ebits = *eps_p;
    const float eps = (ebits >= 1 && ebits <= (1 << 20)) ? (float)ebits
                                                         : __int_as_float(ebits);
    const float inv_eps = 1.0f / eps;

    // stage this block's 8 M rows into LDS (once; survives cache invalidations)
    {
        const float4* Mrow = (const float4*)(Mm + (size_t)row * NN);
        float4* ml4 = (float4*)m_lds[wave];
        #pragma unroll
        for (int k = 0; k < 8; ++k) {
            const int idx = (k << 6) + lane;
            ml4[idx] = Mrow[idx];
        }
    }

    cg::this_grid().sync();   // init visible device-wide; tag protocol takes over

    float* f_final = nullptr;
    bool   aborted = false;

    for (int t = 0; ; ++t) {
        float* fl = (t & 1) ? fB : fA;
        unsigned long long* gb  = (t & 1) ? gb1 : gb0;
        unsigned long long* gbn = (t & 1) ? gb0 : gb1;

        // ---- verify+stage: spin-load pair words until all tags == t.
        // The loads ARE the f staging; value+tag share one 8B word -> no fences.
        {
            bool ok0 = false, ok1 = false, ok2 = false, ok3 = false;
            int violloc = 0;
            const unsigned int want = (unsigned int)t;
            int guard = 0;
            for (;;) {
                if (!ok0) {
                    unsigned long long p = __hip_atomic_load(&gb[tid], __ATOMIC_RELAXED, __HIP_MEMORY_SCOPE_AGENT);
                    if ((unsigned int)(p >> 33) == want) {
                        ok0 = true; violloc |= (int)((p >> 32) & 1ULL);
                        fl[tid] = __uint_as_float((unsigned int)p);
                    }
                }
                if (!ok1) {
                    unsigned long long p = __hip_atomic_load(&gb[tid + 512], __ATOMIC_RELAXED, __HIP_MEMORY_SCOPE_AGENT);
                    if ((unsigned int)(p >> 33) == want) {
                        ok1 = true; violloc |= (int)((p >> 32) & 1ULL);
                        fl[tid + 512] = __uint_as_float((unsigned int)p);
                    }
                }
                if (!ok2) {
                    unsigned long long p = __hip_atomic_load(&gb[tid + 1024], __ATOMIC_RELAXED, __HIP_MEMORY_SCOPE_AGENT);
                    if ((unsigned int)(p >> 33) == want) {
                        ok2 = true; violloc |= (int)((p >> 32) & 1ULL);
                        fl[tid + 1024] = __uint_as_float((unsigned int)p);
                    }
                }
                if (!ok3) {
                    unsigned long long p = __hip_atomic_load(&gb[tid + 1536], __ATOMIC_RELAXED, __HIP_MEMORY_SCOPE_AGENT);
                    if ((unsigned int)(p >> 33) == want) {
                        ok3 = true; violloc |= (int)((p >> 32) & 1ULL);
                        fl[tid + 1536] = __uint_as_float((unsigned int)p);
                    }
                }
                const int anybad = __any(!(ok0 && ok1 && ok2 && ok3)) ? 1 : 0;
                if (lane == 0) s_stale[wave] = anybad;
                // anti-hang: poll global abort flag occasionally
                if (tid == 0 && (guard & 63) == 63)
                    if (__hip_atomic_load(abortp, __ATOMIC_RELAXED, __HIP_MEMORY_SCOPE_AGENT))
                        s_abort = 1;
                __syncthreads();
                const int blk = s_stale[0] | s_stale[1] | s_stale[2] | s_stale[3]
                              | s_stale[4] | s_stale[5] | s_stale[6] | s_stale[7];
                const int ab  = s_abort;
                __syncthreads();
                if (!blk) break;
                if (ab || ++guard > SPIN_LIMIT) {   // fail loud, never hang
                    if (tid == 0)
                        __hip_atomic_store(abortp, 1, __ATOMIC_RELAXED, __HIP_MEMORY_SCOPE_AGENT);
                    aborted = true;
                    break;
                }
            }
            if (aborted) { f_final = fl; break; }   // garbage f -> absmax screams

            // convergence decision: viol bits ride tags ≡2 (mod 10) (check at
            // k=t-2 on f_{t-1}); consume when t%10==2. bv is bit-identical in
            // every block (all read the same 2048 words).
            if ((t % 10) == 2) {
                const int wv = __any(violloc != 0) ? 1 : 0;
                if (lane == 0) s_viol[wave] = wv;
                __syncthreads();
                const int bv = s_viol[0] | s_viol[1] | s_viol[2] | s_viol[3]
                             | s_viol[4] | s_viol[5] | s_viol[6] | s_viol[7];
                if (bv == 0) {            // converged: final f = f_{t-1} (other LDS buf)
                    f_final = (t & 1) ? fA : fB;
                    break;
                }
            }
        }
        if (t == MAX_ITER) {              // exhausted: final f = f_1000 (just staged)
            f_final = fl;
            break;
        }

        // ---- compute f_{t+1}[row] = 0.5*(f_t[row] - eps*LSE_j((f_t[j]-M[row][j])/eps))
        const float4* ml4 = (const float4*)m_lds[wave];
        const float4* fl4 = (const float4*)fl;
        float x[32];
        float mloc = -INFINITY;
        #pragma unroll
        for (int k = 0; k < 8; ++k) {
            const int idx = (k << 6) + lane;
            const float4 mv = ml4[idx];
            const float4 f4 = fl4[idx];
            const float x0 = (f4.x - mv.x) * inv_eps;
            const float x1 = (f4.y - mv.y) * inv_eps;
            const float x2 = (f4.z - mv.z) * inv_eps;
            const float x3 = (f4.w - mv.w) * inv_eps;
            x[4*k+0] = x0; x[4*k+1] = x1; x[4*k+2] = x2; x[4*k+3] = x3;
            mloc = fmaxf(mloc, fmaxf(fmaxf(x0, x1), fmaxf(x2, x3)));
        }
        float mw = mloc;
        #pragma unroll
        for (int off = 32; off; off >>= 1)
            mw = fmaxf(mw, __shfl_down(mw, off));
        mw = __shfl(mw, 0);
        float s = 0.0f;
        #pragma unroll
        for (int k = 0; k < 32; ++k) s += expf(x[k] - mw);
        #pragma unroll
        for (int off = 32; off; off >>= 1)
            s += __shfl_down(s, off);

        if (lane == 0) {
            const float L  = mw + logf(s);
            const float fi = fl[row];
            const float fn = 0.5f * (fi - eps * L);
            unsigned int viol = 0u;
            if ((t % 10) == 1) {   // reference check at k=t-1 on f_t
                const float rs = expf(fi * inv_eps + L);
                viol = (fabsf(rs - 1.0f) < TOLF) ? 0u : 1u;
            }
            __hip_atomic_store(&gbn[row], pack_pair((unsigned int)(t + 1), viol, fn),
                               __ATOMIC_RELAXED, __HIP_MEMORY_SCOPE_AGENT);
        }
        // no barrier: next pass's verify IS the synchronization
    }

    // ---- loss epilogue: sum_ij g*(log g - logQ - 1) + exp(logQ); logQ=(f_i+f_j-M)/eps
    __syncthreads();
    const float4* Grow = (const float4*)(Gg + (size_t)row * NN);
    const float4* ml4  = (const float4*)m_lds[wave];
    const float4* fl4  = (const float4*)f_final;
    const float   fi   = f_final[row];
    double lsum = 0.0;
    #pragma unroll
    for (int k = 0; k < 8; ++k) {
        const int idx = (k << 6) + lane;
        const float4 mv = ml4[idx];
        const float4 gv = Grow[idx];
        const float4 f4 = fl4[idx];
        {
            const float lq = (fi + f4.x - mv.x) * inv_eps;
            lsum += (double)(gv.x * (logf(gv.x) - lq - 1.0f) + expf(lq));
        }
        {
            const float lq = (fi + f4.y - mv.y) * inv_eps;
            lsum += (double)(gv.y * (logf(gv.y) - lq - 1.0f) + expf(lq));
        }
        {
            const float lq = (fi + f4.z - mv.z) * inv_eps;
            lsum += (double)(gv.z * (logf(gv.z) - lq - 1.0f) + expf(lq));
        }
        {
            const float lq = (fi + f4.w - mv.w) * inv_eps;
            lsum += (double)(gv.w * (logf(gv.w) - lq - 1.0f) + expf(lq));
        }
    }
    #pragma unroll
    for (int off = 32; off; off >>= 1)
        lsum += __shfl_down(lsum, off);

    if (lane == 0) s_part[wave] = lsum;
    __syncthreads();
    if (tid == 0) {
        double b = 0.0;
        #pragma unroll
        for (int w = 0; w < WPB; ++w) b += s_part[w];
        atomicAdd(acc, b);
        __threadfence();
        const int prev = __hip_atomic_fetch_add(done_cnt, 1,
                                                __ATOMIC_RELAXED, __HIP_MEMORY_SCOPE_AGENT);
        if (prev == NBLK - 1) {   // last block finalizes
            __threadfence();
            const double total = __hip_atomic_load(acc, __ATOMIC_RELAXED,
                                                   __HIP_MEMORY_SCOPE_AGENT);
            out[0] = (float)(250.0 * total);
        }
    }
}

extern "C" void kernel_launch(void* const* d_in, const int* in_sizes, int n_in,
                              void* d_out, int out_size, void* d_ws, size_t ws_size,
                              hipStream_t stream)
{
    const float* Mm    = (const float*)d_in[0];
    const float* Gg    = (const float*)d_in[1];
    const int*   eps_p = (const int*)d_in[2];
    float* out = (float*)d_out;
    unsigned long long* ws64 = (unsigned long long*)d_ws;

    void* args[] = { (void*)&Mm, (void*)&Gg, (void*)&eps_p, (void*)&out, (void*)&ws64 };
    hipLaunchCooperativeKernel((void*)xgr_sinkhorn, dim3(NBLK), dim3(TPB),
                               args, 0, stream);
}